// Round 4
// baseline (126.727 us; speedup 1.0000x reference)
//
#include <hip/hip_runtime.h>

// B=16, C=64, H=256, W=256, K=2 non-overlapping vector max-pool.
// p = sqrt(u^2+v^2); per 2x2 window pick (u,v) at argmax(p), first-max.
// sqrt monotonic -> compare squared magnitudes; strict > keeps first-max.
//
// R3: one thread per 4 output pixels. 8x 16B loads (128 B/thread, high MLP),
// 2x 16B non-temporal stores. pick2x2 returns by value (refs can't bind to
// ext_vector elements).

typedef float f32x4 __attribute__((ext_vector_type(4)));

#define BC (16 * 64)
#define W_IN 256
#define IN_PLANE (256 * 256)
#define W_OUT 128
#define H_OUT 128
#define OUT_PLANE (W_OUT * H_OUT)
#define QUADS_PER_ROW (W_OUT / 4)                 // 32
#define N_THREADS (BC * H_OUT * QUADS_PER_ROW)    // 4,194,304

struct UV { float u, v; };

__device__ __forceinline__ UV pick2x2(float ua, float ub, float uc, float ud,
                                      float va, float vb, float vc, float vd) {
  // candidate order: TL(a), TR(b), BL(c), BR(d) — first-max via strict >
  float ma = ua * ua + va * va;
  float mb = ub * ub + vb * vb;
  float mc = uc * uc + vc * vc;
  float md = ud * ud + vd * vd;
  float bm = ma, bu = ua, bv = va;
  if (mb > bm) { bm = mb; bu = ub; bv = vb; }
  if (mc > bm) { bm = mc; bu = uc; bv = vc; }
  if (md > bm) { bm = md; bu = ud; bv = vd; }
  return {bu, bv};
}

__global__ __launch_bounds__(256) void vector_maxpool_kernel(
    const float* __restrict__ u, const float* __restrict__ v,
    float* __restrict__ uo, float* __restrict__ vo) {
  int tid = blockIdx.x * blockDim.x + threadIdx.x;

  int q  = tid & (QUADS_PER_ROW - 1);   // quad index within output row [0,32)
  int ho = (tid >> 5) & (H_OUT - 1);    // output row [0,128)
  int bc = tid >> 12;                   // fused b*c [0,1024)

  size_t in_base = (size_t)bc * IN_PLANE + (size_t)(2 * ho) * W_IN + (size_t)q * 8;

  // 8 independent 16B loads — full MLP, fully coalesced across the wave
  const f32x4 u00 = *(const f32x4*)(u + in_base);
  const f32x4 u01 = *(const f32x4*)(u + in_base + 4);
  const f32x4 u10 = *(const f32x4*)(u + in_base + W_IN);
  const f32x4 u11 = *(const f32x4*)(u + in_base + W_IN + 4);
  const f32x4 v00 = *(const f32x4*)(v + in_base);
  const f32x4 v01 = *(const f32x4*)(v + in_base + 4);
  const f32x4 v10 = *(const f32x4*)(v + in_base + W_IN);
  const f32x4 v11 = *(const f32x4*)(v + in_base + W_IN + 4);

  UV a = pick2x2(u00.x, u00.y, u10.x, u10.y, v00.x, v00.y, v10.x, v10.y);
  UV b = pick2x2(u00.z, u00.w, u10.z, u10.w, v00.z, v00.w, v10.z, v10.w);
  UV c = pick2x2(u01.x, u01.y, u11.x, u11.y, v01.x, v01.y, v11.x, v11.y);
  UV d = pick2x2(u01.z, u01.w, u11.z, u11.w, v01.z, v01.w, v11.z, v11.w);

  f32x4 uout = {a.u, b.u, c.u, d.u};
  f32x4 vout = {a.v, b.v, c.v, d.v};

  size_t out_idx = (size_t)bc * OUT_PLANE + (size_t)ho * W_OUT + (size_t)q * 4;
  __builtin_nontemporal_store(uout, (f32x4*)(uo + out_idx));
  __builtin_nontemporal_store(vout, (f32x4*)(vo + out_idx));
}

extern "C" void kernel_launch(void* const* d_in, const int* in_sizes, int n_in,
                              void* d_out, int out_size, void* d_ws, size_t ws_size,
                              hipStream_t stream) {
  const float* u = (const float*)d_in[0];
  const float* v = (const float*)d_in[1];
  float* uo = (float*)d_out;
  float* vo = uo + (size_t)BC * OUT_PLANE;

  int threads = 256;
  int blocks = N_THREADS / threads;  // 16384
  vector_maxpool_kernel<<<blocks, threads, 0, stream>>>(u, v, uo, vo);
}